// Round 1
// baseline (771.312 us; speedup 1.0000x reference)
//
#include <hip/hip_runtime.h>
#include <hip/hip_bf16.h>

typedef __bf16 bf16;
typedef __attribute__((ext_vector_type(8))) __bf16 bf16x8;
typedef __attribute__((ext_vector_type(4))) __bf16 bf16x4;
typedef __attribute__((ext_vector_type(4))) float f32x4;

#define AS1 __attribute__((address_space(1)))
#define AS3 __attribute__((address_space(3)))

// ---------------- weight fp32 -> bf16 ----------------
__global__ void cvt_w(const float* __restrict__ a, bf16* __restrict__ o) {
    int i = blockIdx.x * 256 + threadIdx.x;   // grid 256 -> 65536 elems
    o[i] = (bf16)a[i];
}

// ---------------- GroupNorm stats: one block per (b,g) ----------------
__global__ void gn_stats(const float* __restrict__ x, float* __restrict__ musd) {
    const int bg = blockIdx.x;                       // b*32+g ; group slab is contiguous
    const float4* p = (const float4*)(x + (long)bg * 32768);
    float s = 0.f, ss = 0.f;
    for (int i = threadIdx.x; i < 8192; i += 256) {
        float4 v = p[i];
        s  += v.x + v.y + v.z + v.w;
        ss += v.x*v.x + v.y*v.y + v.z*v.z + v.w*v.w;
    }
    for (int o = 32; o; o >>= 1) { s += __shfl_down(s, o); ss += __shfl_down(ss, o); }
    __shared__ float rs[4], rss[4];
    if ((threadIdx.x & 63) == 0) { rs[threadIdx.x >> 6] = s; rss[threadIdx.x >> 6] = ss; }
    __syncthreads();
    if (threadIdx.x == 0) {
        s  = rs[0] + rs[1] + rs[2] + rs[3];
        ss = rss[0] + rss[1] + rss[2] + rss[3];
        float mu  = s * (1.f / 32768.f);
        float var = ss * (1.f / 32768.f) - mu * mu;
        musd[bg * 2]     = mu;
        musd[bg * 2 + 1] = rsqrtf(var + 1e-5f);
    }
}

// ---------------- GroupNorm apply + transpose: x[b,c,i] -> hT[b,i,c] bf16 ----------------
__global__ void gn_apply_t(const float* __restrict__ x, const float* __restrict__ musd,
                           const float* __restrict__ gw, const float* __restrict__ gb,
                           bf16* __restrict__ hT) {
    const int b  = blockIdx.x >> 6;
    const int i0 = (blockIdx.x & 63) << 6;           // 64 pixels per block
    __shared__ bf16 tile[256][65];                   // pad 65 -> 4-way max on read
    const int lane = threadIdx.x & 63, wv = threadIdx.x >> 6;
    const long xb = (long)b * (256L * 4096);
    for (int r = 0; r < 64; ++r) {
        int c = wv * 64 + r;
        int g = c >> 3;
        float mu   = musd[(b * 32 + g) * 2];
        float rstd = musd[(b * 32 + g) * 2 + 1];
        float v = x[xb + (long)c * 4096 + i0 + lane];
        tile[c][lane] = (bf16)((v - mu) * rstd * gw[c] + gb[c]);
    }
    __syncthreads();
    for (int it = 0; it < 8; ++it) {
        int q  = it * 256 + threadIdx.x;             // 2048 16B chunks
        int il = q >> 5;
        int c8 = (q & 31) << 3;
        bf16x8 v;
        #pragma unroll
        for (int e = 0; e < 8; ++e) v[e] = tile[c8 + e][il];
        *(bf16x8*)(&hT[((long)b * 4096 + i0 + il) * 256 + c8]) = v;
    }
}

// ---------------- BT-GEMM: C[m,n] = alpha * sum_k A[m,k]*B[n,k] (+bias)(+resid) ----------------
// 128x128 tile, BK=64, 4 waves, 16x16x32 bf16 MFMA, global_load_lds w/ xor-swizzle.
template<int BIAS_MODE /*0 none,1 row,2 col*/, bool RESID, typename OutT>
__launch_bounds__(256)
__global__ void gemm_bt(const bf16* __restrict__ A, const bf16* __restrict__ B,
                        OutT* __restrict__ C,
                        const float* __restrict__ bias, const float* __restrict__ resid,
                        int M, int N, int K, int lda, int ldb, int ldc,
                        long sA, long sB, long sC, long sR, float alpha) {
    __shared__ __align__(1024) char lds[32768];
    const int z = blockIdx.z;
    A += (long)z * sA; B += (long)z * sB; C += (long)z * sC;
    const float* Rp = resid + (RESID ? (long)z * sR : 0);

    const int m0 = blockIdx.y * 128;
    const int n0 = blockIdx.x * 128;
    const int lane = threadIdx.x & 63;
    const int wv = threadIdx.x >> 6;
    const int wr = wv >> 1, wc = wv & 1;

    f32x4 acc[4][4];
    #pragma unroll
    for (int i = 0; i < 4; ++i)
        #pragma unroll
        for (int j = 0; j < 4; ++j) acc[i][j] = f32x4{0.f, 0.f, 0.f, 0.f};

    char* ldsA = lds;
    char* ldsB = lds + 16384;

    for (int k0 = 0; k0 < K; k0 += 64) {
        #pragma unroll
        for (int c = 0; c < 4; ++c) {
            int chunk  = wv * 4 + c;
            int ldsOff = chunk * 1024;                  // wave-uniform dest
            int myOff  = ldsOff + lane * 16;
            int row    = myOff >> 7;                    // tile row this lane fills
            int colB   = (myOff & 127) ^ ((row & 7) << 4);  // inverse-swizzled source
            const char* srcA = (const char*)(A + (long)(m0 + row) * lda + k0) + colB;
            __builtin_amdgcn_global_load_lds((const AS1 void*)srcA,
                                             (AS3 void*)(ldsA + ldsOff), 16, 0, 0);
            const char* srcB = (const char*)(B + (long)(n0 + row) * ldb + k0) + colB;
            __builtin_amdgcn_global_load_lds((const AS1 void*)srcB,
                                             (AS3 void*)(ldsB + ldsOff), 16, 0, 0);
        }
        __syncthreads();
        #pragma unroll
        for (int kk = 0; kk < 2; ++kk) {
            bf16x8 aF[4], bF[4];
            const int kb = kk * 64 + (lane >> 4) * 16;
            #pragma unroll
            for (int mf = 0; mf < 4; ++mf) {
                int row = wr * 64 + mf * 16 + (lane & 15);
                aF[mf] = *(const bf16x8*)(ldsA + row * 128 + (kb ^ ((row & 7) << 4)));
            }
            #pragma unroll
            for (int nf = 0; nf < 4; ++nf) {
                int row = wc * 64 + nf * 16 + (lane & 15);
                bF[nf] = *(const bf16x8*)(ldsB + row * 128 + (kb ^ ((row & 7) << 4)));
            }
            #pragma unroll
            for (int mf = 0; mf < 4; ++mf)
                #pragma unroll
                for (int nf = 0; nf < 4; ++nf)
                    acc[mf][nf] = __builtin_amdgcn_mfma_f32_16x16x32_bf16(
                        aF[mf], bF[nf], acc[mf][nf], 0, 0, 0);
        }
        __syncthreads();
    }

    #pragma unroll
    for (int mf = 0; mf < 4; ++mf) {
        #pragma unroll
        for (int nf = 0; nf < 4; ++nf) {
            int col   = n0 + wc * 64 + nf * 16 + (lane & 15);
            int rbase = m0 + wr * 64 + mf * 16 + (lane >> 4) * 4;
            float cb = (BIAS_MODE == 2) ? bias[col] : 0.f;
            #pragma unroll
            for (int e = 0; e < 4; ++e) {
                int row = rbase + e;
                float v = acc[mf][nf][e] * alpha;
                if (BIAS_MODE == 1) v += bias[row];
                if (BIAS_MODE == 2) v += cb;
                long off = (long)row * ldc + col;
                if (RESID) v += Rp[off];
                C[off] = (OutT)v;
            }
        }
    }
}

// ---------------- column softmax over ST[j,i] (softmax along j for each i) ----------------
__global__ void smax_part(const float* __restrict__ S, float* __restrict__ part) {
    int i  = blockIdx.x * 256 + threadIdx.x;     // column
    int j0 = blockIdx.y * 128;
    float m = -1e30f, l = 0.f;
    for (int j = j0; j < j0 + 128; ++j) {
        float v  = S[(long)j * 4096 + i];
        float mn = fmaxf(m, v);
        l = l * __expf(m - mn) + __expf(v - mn);
        m = mn;
    }
    part[(blockIdx.y * 2) * 4096 + i]     = m;
    part[(blockIdx.y * 2 + 1) * 4096 + i] = l;
}

__global__ void smax_merge(const float* __restrict__ part, float* __restrict__ ml) {
    int i = blockIdx.x * 256 + threadIdx.x;
    float m = -1e30f, l = 0.f;
    for (int c = 0; c < 32; ++c) {
        float mc = part[(c * 2) * 4096 + i];
        float lc = part[(c * 2 + 1) * 4096 + i];
        float mn = fmaxf(m, mc);
        l = l * __expf(m - mn) + lc * __expf(mc - mn);
        m = mn;
    }
    ml[i] = m;
    ml[4096 + i] = 1.f / l;
}

__global__ void smax_norm(const float* __restrict__ S, const float* __restrict__ ml,
                          bf16* __restrict__ PT) {
    int idx4 = blockIdx.x * 256 + threadIdx.x;   // grid 16384 -> 4,194,304 float4s
    float4 v = ((const float4*)S)[idx4];
    int i = (idx4 * 4) & 4095;
    float4 mm = ((const float4*)ml)[i >> 2];
    float4 ll = ((const float4*)(ml + 4096))[i >> 2];
    bf16x4 o;
    o[0] = (bf16)(__expf(v.x - mm.x) * ll.x);
    o[1] = (bf16)(__expf(v.y - mm.y) * ll.y);
    o[2] = (bf16)(__expf(v.z - mm.z) * ll.z);
    o[3] = (bf16)(__expf(v.w - mm.w) * ll.w);
    ((bf16x4*)PT)[idx4] = o;
}

// ---------------- split-K reduce: 4 fp32 partial slabs -> bf16 ----------------
__global__ void reduce4(const float4* __restrict__ p, bf16* __restrict__ out) {
    int idx = blockIdx.x * 256 + threadIdx.x;    // grid 1024 -> 262144 float4s
    float4 a = p[idx], b = p[idx + 262144], c = p[idx + 524288], d = p[idx + 786432];
    bf16x4 o;
    o[0] = (bf16)(a.x + b.x + c.x + d.x);
    o[1] = (bf16)(a.y + b.y + c.y + d.y);
    o[2] = (bf16)(a.z + b.z + c.z + d.z);
    o[3] = (bf16)(a.w + b.w + c.w + d.w);
    ((bf16x4*)out)[idx] = o;
}

extern "C" void kernel_launch(void* const* d_in, const int* in_sizes, int n_in,
                              void* d_out, int out_size, void* d_ws, size_t ws_size,
                              hipStream_t stream) {
    const float* x   = (const float*)d_in[0];
    const float* gnw = (const float*)d_in[1];
    const float* gnb = (const float*)d_in[2];
    const float* wq  = (const float*)d_in[3];
    const float* bq  = (const float*)d_in[4];
    const float* wk  = (const float*)d_in[5];
    const float* bk  = (const float*)d_in[6];
    const float* wv  = (const float*)d_in[7];
    const float* bv  = (const float*)d_in[8];
    const float* wo  = (const float*)d_in[9];
    const float* bo  = (const float*)d_in[10];
    float* out = (float*)d_out;

    char* ws = (char*)d_ws;
    size_t off = 0;
    auto alloc = [&](size_t b) { char* p = ws + off; off += (b + 255) & ~(size_t)255; return p; };

    const long NC = 4096L * 256;          // per-batch [N,C] elems
    bf16* hT  = (bf16*)alloc(8 * NC * 2);
    bf16* qT  = (bf16*)alloc(8 * NC * 2);
    bf16* kT  = (bf16*)alloc(8 * NC * 2);
    bf16* vB  = (bf16*)alloc(8 * NC * 2);   // v[c,i]
    bf16* h2T = (bf16*)alloc(8 * NC * 2);
    bf16* wqb = (bf16*)alloc(65536 * 2);
    bf16* wkb = (bf16*)alloc(65536 * 2);
    bf16* wvb = (bf16*)alloc(65536 * 2);
    bf16* wob = (bf16*)alloc(65536 * 2);
    float* musd = (float*)alloc(256 * 2 * 4);
    float* S    = (float*)alloc(4096L * 4096 * 4);
    bf16*  PT   = (bf16*)alloc(4096L * 4096 * 2);
    float* part = (float*)alloc(64L * 4096 * 4);
    float* ml   = (float*)alloc(2L * 4096 * 4);
    float* pvp  = (float*)alloc(4 * NC * 4);

    cvt_w<<<256, 256, 0, stream>>>(wq, wqb);
    cvt_w<<<256, 256, 0, stream>>>(wk, wkb);
    cvt_w<<<256, 256, 0, stream>>>(wv, wvb);
    cvt_w<<<256, 256, 0, stream>>>(wo, wob);
    gn_stats<<<256, 256, 0, stream>>>(x, musd);
    gn_apply_t<<<512, 256, 0, stream>>>(x, musd, gnw, gnb, hT);

    // qT[i,c] = sum_k hT[i,k] wq[c,k] + bq[c]
    gemm_bt<2, false, bf16><<<dim3(2, 32, 8), 256, 0, stream>>>(
        hT, wqb, qT, bq, nullptr, 4096, 256, 256, 256, 256, 256, NC, 0, NC, 0, 1.f);
    gemm_bt<2, false, bf16><<<dim3(2, 32, 8), 256, 0, stream>>>(
        hT, wkb, kT, bk, nullptr, 4096, 256, 256, 256, 256, 256, NC, 0, NC, 0, 1.f);
    // v[c,i] = sum_k wv[c,k] hT[i,k] + bv[c]
    gemm_bt<1, false, bf16><<<dim3(32, 2, 8), 256, 0, stream>>>(
        wvb, hT, vB, bv, nullptr, 256, 4096, 256, 256, 256, 4096, 0, NC, NC, 0, 1.f);

    for (int b = 0; b < 8; ++b) {
        // ST[j,i] = (1/16) * sum_c kT[j,c] qT[i,c]
        gemm_bt<0, false, float><<<dim3(32, 32, 1), 256, 0, stream>>>(
            kT + b * NC, qT + b * NC, S, nullptr, nullptr,
            4096, 4096, 256, 256, 256, 4096, 0, 0, 0, 0, 0.0625f);
        smax_part<<<dim3(16, 32), 256, 0, stream>>>(S, part);
        smax_merge<<<16, 256, 0, stream>>>(part, ml);
        smax_norm<<<16384, 256, 0, stream>>>(S, ml, PT);
        // h2T[j,c] = sum_i PT[j,i] v[c,i]   (split-K over grid.z)
        gemm_bt<0, false, float><<<dim3(2, 32, 4), 256, 0, stream>>>(
            PT, vB + b * NC, pvp, nullptr, nullptr,
            4096, 256, 1024, 4096, 4096, 256, 1024, 1024, NC, 0, 1.f);
        reduce4<<<1024, 256, 0, stream>>>((const float4*)pvp, h2T + b * NC);
    }

    // out[o,j] = x[o,j] + bo[o] + sum_c wo[o,c] h2T[j,c]
    gemm_bt<1, true, float><<<dim3(32, 2, 8), 256, 0, stream>>>(
        wob, h2T, out, bo, x, 256, 4096, 256, 256, 256, 4096, 0, NC, NC, NC, 1.f);
}

// Round 2
// 499.384 us; speedup vs baseline: 1.5445x; 1.5445x over previous
//
#include <hip/hip_runtime.h>
#include <hip/hip_bf16.h>

typedef __bf16 bf16;
typedef __attribute__((ext_vector_type(8))) __bf16 bf16x8;
typedef __attribute__((ext_vector_type(4))) __bf16 bf16x4;
typedef __attribute__((ext_vector_type(4))) float f32x4;

#define AS1 __attribute__((address_space(1)))
#define AS3 __attribute__((address_space(3)))

// ---------------- weight fp32 -> bf16 ----------------
__global__ void cvt_w(const float* __restrict__ a, bf16* __restrict__ o) {
    int i = blockIdx.x * 256 + threadIdx.x;   // grid 256 -> 65536 elems
    o[i] = (bf16)a[i];
}

// ---------------- GroupNorm stats: one block per (b,g) ----------------
__global__ void gn_stats(const float* __restrict__ x, float* __restrict__ musd) {
    const int bg = blockIdx.x;                       // b*32+g ; group slab is contiguous
    const float4* p = (const float4*)(x + (long)bg * 32768);
    float s = 0.f, ss = 0.f;
    for (int i = threadIdx.x; i < 8192; i += 256) {
        float4 v = p[i];
        s  += v.x + v.y + v.z + v.w;
        ss += v.x*v.x + v.y*v.y + v.z*v.z + v.w*v.w;
    }
    for (int o = 32; o; o >>= 1) { s += __shfl_down(s, o); ss += __shfl_down(ss, o); }
    __shared__ float rs[4], rss[4];
    if ((threadIdx.x & 63) == 0) { rs[threadIdx.x >> 6] = s; rss[threadIdx.x >> 6] = ss; }
    __syncthreads();
    if (threadIdx.x == 0) {
        s  = rs[0] + rs[1] + rs[2] + rs[3];
        ss = rss[0] + rss[1] + rss[2] + rss[3];
        float mu  = s * (1.f / 32768.f);
        float var = ss * (1.f / 32768.f) - mu * mu;
        musd[bg * 2]     = mu;
        musd[bg * 2 + 1] = rsqrtf(var + 1e-5f);
    }
}

// ---------------- GroupNorm apply + transpose: x[b,c,i] -> hT[b,i,c] bf16 ----------------
__global__ void gn_apply_t(const float* __restrict__ x, const float* __restrict__ musd,
                           const float* __restrict__ gw, const float* __restrict__ gb,
                           bf16* __restrict__ hT) {
    const int b  = blockIdx.x >> 6;
    const int i0 = (blockIdx.x & 63) << 6;           // 64 pixels per block
    __shared__ bf16 tile[256][65];
    const int lane = threadIdx.x & 63, wv = threadIdx.x >> 6;
    const long xb = (long)b * (256L * 4096);
    for (int r = 0; r < 64; ++r) {
        int c = wv * 64 + r;
        int g = c >> 3;
        float mu   = musd[(b * 32 + g) * 2];
        float rstd = musd[(b * 32 + g) * 2 + 1];
        float v = x[xb + (long)c * 4096 + i0 + lane];
        tile[c][lane] = (bf16)((v - mu) * rstd * gw[c] + gb[c]);
    }
    __syncthreads();
    for (int it = 0; it < 8; ++it) {
        int q  = it * 256 + threadIdx.x;             // 2048 16B chunks
        int il = q >> 5;
        int c8 = (q & 31) << 3;
        bf16x8 v;
        #pragma unroll
        for (int e = 0; e < 8; ++e) v[e] = tile[c8 + e][il];
        *(bf16x8*)(&hT[((long)b * 4096 + i0 + il) * 256 + c8]) = v;
    }
}

// ---------------- BT-GEMM: C[m,n] = alpha * sum_k A[m,k]*B[n,k] (+bias)(+resid) ----------------
template<int BIAS_MODE /*0 none,1 row,2 col*/, bool RESID, typename OutT>
__launch_bounds__(256)
__global__ void gemm_bt(const bf16* __restrict__ A, const bf16* __restrict__ B,
                        OutT* __restrict__ C,
                        const float* __restrict__ bias, const float* __restrict__ resid,
                        int M, int N, int K, int lda, int ldb, int ldc,
                        long sA, long sB, long sC, long sR, float alpha) {
    __shared__ __align__(1024) char lds[32768];
    const int z = blockIdx.z;
    A += (long)z * sA; B += (long)z * sB; C += (long)z * sC;
    const float* Rp = resid + (RESID ? (long)z * sR : 0);

    const int m0 = blockIdx.y * 128;
    const int n0 = blockIdx.x * 128;
    const int lane = threadIdx.x & 63;
    const int wv = threadIdx.x >> 6;
    const int wr = wv >> 1, wc = wv & 1;

    f32x4 acc[4][4];
    #pragma unroll
    for (int i = 0; i < 4; ++i)
        #pragma unroll
        for (int j = 0; j < 4; ++j) acc[i][j] = f32x4{0.f, 0.f, 0.f, 0.f};

    char* ldsA = lds;
    char* ldsB = lds + 16384;

    for (int k0 = 0; k0 < K; k0 += 64) {
        #pragma unroll
        for (int c = 0; c < 4; ++c) {
            int chunk  = wv * 4 + c;
            int ldsOff = chunk * 1024;                  // wave-uniform dest
            int myOff  = ldsOff + lane * 16;
            int row    = myOff >> 7;
            int colB   = (myOff & 127) ^ ((row & 7) << 4);  // inverse-swizzled source
            const char* srcA = (const char*)(A + (long)(m0 + row) * lda + k0) + colB;
            __builtin_amdgcn_global_load_lds((const AS1 void*)srcA,
                                             (AS3 void*)(ldsA + ldsOff), 16, 0, 0);
            const char* srcB = (const char*)(B + (long)(n0 + row) * ldb + k0) + colB;
            __builtin_amdgcn_global_load_lds((const AS1 void*)srcB,
                                             (AS3 void*)(ldsB + ldsOff), 16, 0, 0);
        }
        __syncthreads();
        #pragma unroll
        for (int kk = 0; kk < 2; ++kk) {
            bf16x8 aF[4], bF[4];
            const int kb = kk * 64 + (lane >> 4) * 16;
            #pragma unroll
            for (int mf = 0; mf < 4; ++mf) {
                int row = wr * 64 + mf * 16 + (lane & 15);
                aF[mf] = *(const bf16x8*)(ldsA + row * 128 + (kb ^ ((row & 7) << 4)));
            }
            #pragma unroll
            for (int nf = 0; nf < 4; ++nf) {
                int row = wc * 64 + nf * 16 + (lane & 15);
                bF[nf] = *(const bf16x8*)(ldsB + row * 128 + (kb ^ ((row & 7) << 4)));
            }
            #pragma unroll
            for (int mf = 0; mf < 4; ++mf)
                #pragma unroll
                for (int nf = 0; nf < 4; ++nf)
                    acc[mf][nf] = __builtin_amdgcn_mfma_f32_16x16x32_bf16(
                        aF[mf], bF[nf], acc[mf][nf], 0, 0, 0);
        }
        __syncthreads();
    }

    #pragma unroll
    for (int mf = 0; mf < 4; ++mf) {
        #pragma unroll
        for (int nf = 0; nf < 4; ++nf) {
            int col   = n0 + wc * 64 + nf * 16 + (lane & 15);
            int rbase = m0 + wr * 64 + mf * 16 + (lane >> 4) * 4;
            float cb = (BIAS_MODE == 2) ? bias[col] : 0.f;
            #pragma unroll
            for (int e = 0; e < 4; ++e) {
                int row = rbase + e;
                float v = acc[mf][nf][e] * alpha;
                if (BIAS_MODE == 1) v += bias[row];
                if (BIAS_MODE == 2) v += cb;
                long off = (long)row * ldc + col;
                if (RESID) v += Rp[off];
                C[off] = (OutT)v;
            }
        }
    }
}

// ---------------- QK GEMM + fused exp + column partial sums ----------------
// P[j,i] = exp(0.0625 * sum_c kT[j,c] qT[i,c]); part[jblk][i] = sum_{j in block} P[j,i]
__launch_bounds__(256)
__global__ void gemm_qk_exp(const bf16* __restrict__ A, const bf16* __restrict__ B,
                            bf16* __restrict__ P, float* __restrict__ part) {
    __shared__ __align__(1024) char lds[34816];   // k-loop: 32KB; epi: bf16[128][132]=33792 + cs 1KB
    const int m0 = blockIdx.y * 128;
    const int n0 = blockIdx.x * 128;
    const int lane = threadIdx.x & 63;
    const int wv = threadIdx.x >> 6;
    const int wr = wv >> 1, wc = wv & 1;

    f32x4 acc[4][4];
    #pragma unroll
    for (int i = 0; i < 4; ++i)
        #pragma unroll
        for (int j = 0; j < 4; ++j) acc[i][j] = f32x4{0.f, 0.f, 0.f, 0.f};

    char* ldsA = lds;
    char* ldsB = lds + 16384;

    for (int k0 = 0; k0 < 256; k0 += 64) {
        #pragma unroll
        for (int c = 0; c < 4; ++c) {
            int chunk  = wv * 4 + c;
            int ldsOff = chunk * 1024;
            int myOff  = ldsOff + lane * 16;
            int row    = myOff >> 7;
            int colB   = (myOff & 127) ^ ((row & 7) << 4);
            const char* srcA = (const char*)(A + (long)(m0 + row) * 256 + k0) + colB;
            __builtin_amdgcn_global_load_lds((const AS1 void*)srcA,
                                             (AS3 void*)(ldsA + ldsOff), 16, 0, 0);
            const char* srcB = (const char*)(B + (long)(n0 + row) * 256 + k0) + colB;
            __builtin_amdgcn_global_load_lds((const AS1 void*)srcB,
                                             (AS3 void*)(ldsB + ldsOff), 16, 0, 0);
        }
        __syncthreads();
        #pragma unroll
        for (int kk = 0; kk < 2; ++kk) {
            bf16x8 aF[4], bF[4];
            const int kb = kk * 64 + (lane >> 4) * 16;
            #pragma unroll
            for (int mf = 0; mf < 4; ++mf) {
                int row = wr * 64 + mf * 16 + (lane & 15);
                aF[mf] = *(const bf16x8*)(ldsA + row * 128 + (kb ^ ((row & 7) << 4)));
            }
            #pragma unroll
            for (int nf = 0; nf < 4; ++nf) {
                int row = wc * 64 + nf * 16 + (lane & 15);
                bF[nf] = *(const bf16x8*)(ldsB + row * 128 + (kb ^ ((row & 7) << 4)));
            }
            #pragma unroll
            for (int mf = 0; mf < 4; ++mf)
                #pragma unroll
                for (int nf = 0; nf < 4; ++nf)
                    acc[mf][nf] = __builtin_amdgcn_mfma_f32_16x16x32_bf16(
                        aF[mf], bF[nf], acc[mf][nf], 0, 0, 0);
        }
        __syncthreads();
    }

    // epilogue: exp, column sums, LDS-transposed coalesced bf16 write
    bf16*  pt = (bf16*)lds;                 // [128][132]
    float* cs = (float*)(lds + 33792);      // [2][128]
    float s[4] = {0.f, 0.f, 0.f, 0.f};
    #pragma unroll
    for (int mf = 0; mf < 4; ++mf) {
        #pragma unroll
        for (int nf = 0; nf < 4; ++nf) {
            int col = wc * 64 + nf * 16 + (lane & 15);
            int rb  = wr * 64 + mf * 16 + (lane >> 4) * 4;
            #pragma unroll
            for (int e = 0; e < 4; ++e) {
                float ev = __expf(acc[mf][nf][e] * 0.0625f);
                s[nf] += ev;
                pt[(rb + e) * 132 + col] = (bf16)ev;
            }
        }
    }
    #pragma unroll
    for (int nf = 0; nf < 4; ++nf) {
        s[nf] += __shfl_xor(s[nf], 16);
        s[nf] += __shfl_xor(s[nf], 32);
    }
    if (lane < 16) {
        #pragma unroll
        for (int nf = 0; nf < 4; ++nf)
            cs[wr * 128 + wc * 64 + nf * 16 + lane] = s[nf];
    }
    __syncthreads();
    if (threadIdx.x < 128)
        part[blockIdx.y * 4096 + n0 + threadIdx.x] = cs[threadIdx.x] + cs[128 + threadIdx.x];
    #pragma unroll
    for (int it = 0; it < 8; ++it) {
        int q   = it * 256 + threadIdx.x;
        int row = q >> 4;
        int c8  = (q & 15) << 3;
        bf16x8 v = *(const bf16x8*)(pt + row * 132 + c8);
        *(bf16x8*)(&P[(long)(m0 + row) * 4096 + n0 + c8]) = v;
    }
}

// ---------------- rl[i] = 1 / sum_{jblk} part[jblk][i] ----------------
__global__ void rl_calc(const float* __restrict__ part, float* __restrict__ rl) {
    int i = blockIdx.x * 256 + threadIdx.x;
    float s = 0.f;
    #pragma unroll
    for (int p = 0; p < 32; ++p) s += part[p * 4096 + i];
    rl[i] = 1.f / s;
}

// ---------------- vS[c,i] = v[c,i] * rl[i] ----------------
__global__ void v_scale(const bf16* __restrict__ v, const float* __restrict__ rl,
                        bf16* __restrict__ vS) {
    int idx = blockIdx.x * 256 + threadIdx.x;     // grid 512 -> 131072 bf16x8 chunks
    int i0  = (idx * 8) & 4095;
    bf16x8 a = ((const bf16x8*)v)[idx];
    float4 r0 = *(const float4*)(rl + i0);
    float4 r1 = *(const float4*)(rl + i0 + 4);
    bf16x8 o;
    o[0] = (bf16)((float)a[0] * r0.x);
    o[1] = (bf16)((float)a[1] * r0.y);
    o[2] = (bf16)((float)a[2] * r0.z);
    o[3] = (bf16)((float)a[3] * r0.w);
    o[4] = (bf16)((float)a[4] * r1.x);
    o[5] = (bf16)((float)a[5] * r1.y);
    o[6] = (bf16)((float)a[6] * r1.z);
    o[7] = (bf16)((float)a[7] * r1.w);
    ((bf16x8*)vS)[idx] = o;
}

// ---------------- split-K reduce: 4 fp32 partial slabs -> bf16 ----------------
__global__ void reduce4(const float4* __restrict__ p, bf16* __restrict__ out) {
    int idx = blockIdx.x * 256 + threadIdx.x;    // grid 1024 -> 262144 float4s
    float4 a = p[idx], b = p[idx + 262144], c = p[idx + 524288], d = p[idx + 786432];
    bf16x4 o;
    o[0] = (bf16)(a.x + b.x + c.x + d.x);
    o[1] = (bf16)(a.y + b.y + c.y + d.y);
    o[2] = (bf16)(a.z + b.z + c.z + d.z);
    o[3] = (bf16)(a.w + b.w + c.w + d.w);
    ((bf16x4*)out)[idx] = o;
}

extern "C" void kernel_launch(void* const* d_in, const int* in_sizes, int n_in,
                              void* d_out, int out_size, void* d_ws, size_t ws_size,
                              hipStream_t stream) {
    const float* x   = (const float*)d_in[0];
    const float* gnw = (const float*)d_in[1];
    const float* gnb = (const float*)d_in[2];
    const float* wq  = (const float*)d_in[3];
    const float* bq  = (const float*)d_in[4];
    const float* wk  = (const float*)d_in[5];
    const float* bk  = (const float*)d_in[6];
    const float* wv  = (const float*)d_in[7];
    const float* bv  = (const float*)d_in[8];
    const float* wo  = (const float*)d_in[9];
    const float* bo  = (const float*)d_in[10];
    float* out = (float*)d_out;

    char* ws = (char*)d_ws;
    size_t off = 0;
    auto alloc = [&](size_t b) { char* p = ws + off; off += (b + 255) & ~(size_t)255; return p; };

    const long NC = 4096L * 256;          // per-batch [N,C] elems
    bf16* hT  = (bf16*)alloc(8 * NC * 2);
    bf16* qT  = (bf16*)alloc(8 * NC * 2);
    bf16* kT  = (bf16*)alloc(8 * NC * 2);
    bf16* vB  = (bf16*)alloc(8 * NC * 2);   // v[c,i]
    bf16* h2T = (bf16*)alloc(8 * NC * 2);
    bf16* wqb = (bf16*)alloc(65536 * 2);
    bf16* wkb = (bf16*)alloc(65536 * 2);
    bf16* wvb = (bf16*)alloc(65536 * 2);
    bf16* wob = (bf16*)alloc(65536 * 2);
    float* musd = (float*)alloc(256 * 2 * 4);
    bf16*  P    = (bf16*)alloc(4096L * 4096 * 2);   // exp(S)
    float* part = (float*)alloc(32L * 4096 * 4);
    float* rl   = (float*)alloc(4096 * 4);
    bf16*  vS   = (bf16*)alloc(NC * 2);
    float* pvp  = (float*)alloc(4 * NC * 4);

    cvt_w<<<256, 256, 0, stream>>>(wq, wqb);
    cvt_w<<<256, 256, 0, stream>>>(wk, wkb);
    cvt_w<<<256, 256, 0, stream>>>(wv, wvb);
    cvt_w<<<256, 256, 0, stream>>>(wo, wob);
    gn_stats<<<256, 256, 0, stream>>>(x, musd);
    gn_apply_t<<<512, 256, 0, stream>>>(x, musd, gnw, gnb, hT);

    // qT[i,c] = sum_k hT[i,k] wq[c,k] + bq[c]
    gemm_bt<2, false, bf16><<<dim3(2, 32, 8), 256, 0, stream>>>(
        hT, wqb, qT, bq, nullptr, 4096, 256, 256, 256, 256, 256, NC, 0, NC, 0, 1.f);
    gemm_bt<2, false, bf16><<<dim3(2, 32, 8), 256, 0, stream>>>(
        hT, wkb, kT, bk, nullptr, 4096, 256, 256, 256, 256, 256, NC, 0, NC, 0, 1.f);
    // v[c,i] = sum_k wv[c,k] hT[i,k] + bv[c]
    gemm_bt<1, false, bf16><<<dim3(32, 2, 8), 256, 0, stream>>>(
        wvb, hT, vB, bv, nullptr, 256, 4096, 256, 256, 256, 4096, 0, NC, NC, 0, 1.f);

    for (int b = 0; b < 8; ++b) {
        // P[j,i] = exp(ST[j,i]/16), part[jblk][i] partial column sums
        gemm_qk_exp<<<dim3(32, 32), 256, 0, stream>>>(kT + b * NC, qT + b * NC, P, part);
        rl_calc<<<16, 256, 0, stream>>>(part, rl);
        v_scale<<<512, 256, 0, stream>>>(vB + b * NC, rl, vS);
        // h2T[j,c] = sum_i P[j,i] vS[c,i]   (split-K over grid.z)
        gemm_bt<0, false, float><<<dim3(2, 32, 4), 256, 0, stream>>>(
            P, vS, pvp, nullptr, nullptr,
            4096, 256, 1024, 4096, 4096, 256, 1024, 1024, NC, 0, 1.f);
        reduce4<<<1024, 256, 0, stream>>>((const float4*)pvp, h2T + b * NC);
    }

    // out[o,j] = x[o,j] + bo[o] + sum_c wo[o,c] h2T[j,c]
    gemm_bt<1, true, float><<<dim3(32, 2, 8), 256, 0, stream>>>(
        wob, h2T, out, bo, x, 256, 4096, 256, 256, 256, 4096, 0, NC, NC, NC, 1.f);
}

// Round 3
// 381.836 us; speedup vs baseline: 2.0200x; 1.3078x over previous
//
#include <hip/hip_runtime.h>
#include <hip/hip_bf16.h>

typedef __bf16 bf16;
typedef __attribute__((ext_vector_type(8))) __bf16 bf16x8;
typedef __attribute__((ext_vector_type(4))) __bf16 bf16x4;
typedef __attribute__((ext_vector_type(4))) float f32x4;

#define AS1 __attribute__((address_space(1)))
#define AS3 __attribute__((address_space(3)))

// ---------------- all four weights fp32 -> bf16 (one launch) ----------------
__global__ void cvt_w4(const float* __restrict__ a0, const float* __restrict__ a1,
                       const float* __restrict__ a2, const float* __restrict__ a3,
                       bf16* __restrict__ o) {
    int idx = blockIdx.x * 256 + threadIdx.x;       // grid 256 -> 65536 float4s (4 x 65536 floats)
    const float* srcs[4] = {a0, a1, a2, a3};
    float4 v = ((const float4*)srcs[idx >> 14])[idx & 16383];
    bf16x4 r; r[0] = (bf16)v.x; r[1] = (bf16)v.y; r[2] = (bf16)v.z; r[3] = (bf16)v.w;
    ((bf16x4*)o)[idx] = r;
}

// ---------------- GroupNorm stats: one block per (b,g) ----------------
__global__ void gn_stats(const float* __restrict__ x, float* __restrict__ musd) {
    const int bg = blockIdx.x;                       // b*32+g ; group slab is contiguous
    const float4* p = (const float4*)(x + (long)bg * 32768);
    float s = 0.f, ss = 0.f;
    for (int i = threadIdx.x; i < 8192; i += 256) {
        float4 v = p[i];
        s  += v.x + v.y + v.z + v.w;
        ss += v.x*v.x + v.y*v.y + v.z*v.z + v.w*v.w;
    }
    for (int o = 32; o; o >>= 1) { s += __shfl_down(s, o); ss += __shfl_down(ss, o); }
    __shared__ float rs[4], rss[4];
    if ((threadIdx.x & 63) == 0) { rs[threadIdx.x >> 6] = s; rss[threadIdx.x >> 6] = ss; }
    __syncthreads();
    if (threadIdx.x == 0) {
        s  = rs[0] + rs[1] + rs[2] + rs[3];
        ss = rss[0] + rss[1] + rss[2] + rss[3];
        float mu  = s * (1.f / 32768.f);
        float var = ss * (1.f / 32768.f) - mu * mu;
        musd[bg * 2]     = mu;
        musd[bg * 2 + 1] = rsqrtf(var + 1e-5f);
    }
}

// ---------------- GroupNorm apply + transpose: x[b,c,i] -> hT[b,i,c] bf16 ----------------
__global__ void gn_apply_t(const float* __restrict__ x, const float* __restrict__ musd,
                           const float* __restrict__ gw, const float* __restrict__ gb,
                           bf16* __restrict__ hT) {
    const int b  = blockIdx.x >> 6;
    const int i0 = (blockIdx.x & 63) << 6;           // 64 pixels per block
    __shared__ bf16 tile[256][65];
    const int lane = threadIdx.x & 63, wv = threadIdx.x >> 6;
    const long xb = (long)b * (256L * 4096);
    for (int r = 0; r < 64; ++r) {
        int c = wv * 64 + r;
        int g = c >> 3;
        float mu   = musd[(b * 32 + g) * 2];
        float rstd = musd[(b * 32 + g) * 2 + 1];
        float v = x[xb + (long)c * 4096 + i0 + lane];
        tile[c][lane] = (bf16)((v - mu) * rstd * gw[c] + gb[c]);
    }
    __syncthreads();
    for (int it = 0; it < 8; ++it) {
        int q  = it * 256 + threadIdx.x;             // 2048 16B chunks
        int il = q >> 5;
        int c8 = (q & 31) << 3;
        bf16x8 v;
        #pragma unroll
        for (int e = 0; e < 8; ++e) v[e] = tile[c8 + e][il];
        *(bf16x8*)(&hT[((long)b * 4096 + i0 + il) * 256 + c8]) = v;
    }
}

// ---------------- BT-GEMM: C[m,n] = alpha * sum_k A[m,k]*B[n,k] (+bias)(+resid) ----------------
template<int BIAS_MODE /*0 none,1 row,2 col*/, bool RESID, typename OutT>
__launch_bounds__(256)
__global__ void gemm_bt(const bf16* __restrict__ A, const bf16* __restrict__ B,
                        OutT* __restrict__ C,
                        const float* __restrict__ bias, const float* __restrict__ resid,
                        int M, int N, int K, int lda, int ldb, int ldc,
                        long sA, long sB, long sC, long sR, float alpha) {
    __shared__ __align__(1024) char lds[32768];
    const int z = blockIdx.z;
    A += (long)z * sA; B += (long)z * sB; C += (long)z * sC;
    const float* Rp = resid + (RESID ? (long)z * sR : 0);

    const int m0 = blockIdx.y * 128;
    const int n0 = blockIdx.x * 128;
    const int lane = threadIdx.x & 63;
    const int wv = threadIdx.x >> 6;
    const int wr = wv >> 1, wc = wv & 1;

    f32x4 acc[4][4];
    #pragma unroll
    for (int i = 0; i < 4; ++i)
        #pragma unroll
        for (int j = 0; j < 4; ++j) acc[i][j] = f32x4{0.f, 0.f, 0.f, 0.f};

    char* ldsA = lds;
    char* ldsB = lds + 16384;

    for (int k0 = 0; k0 < K; k0 += 64) {
        #pragma unroll
        for (int c = 0; c < 4; ++c) {
            int chunk  = wv * 4 + c;
            int ldsOff = chunk * 1024;                  // wave-uniform dest
            int myOff  = ldsOff + lane * 16;
            int row    = myOff >> 7;
            int colB   = (myOff & 127) ^ ((row & 7) << 4);  // inverse-swizzled source
            const char* srcA = (const char*)(A + (long)(m0 + row) * lda + k0) + colB;
            __builtin_amdgcn_global_load_lds((const AS1 void*)srcA,
                                             (AS3 void*)(ldsA + ldsOff), 16, 0, 0);
            const char* srcB = (const char*)(B + (long)(n0 + row) * ldb + k0) + colB;
            __builtin_amdgcn_global_load_lds((const AS1 void*)srcB,
                                             (AS3 void*)(ldsB + ldsOff), 16, 0, 0);
        }
        __syncthreads();
        #pragma unroll
        for (int kk = 0; kk < 2; ++kk) {
            bf16x8 aF[4], bF[4];
            const int kb = kk * 64 + (lane >> 4) * 16;
            #pragma unroll
            for (int mf = 0; mf < 4; ++mf) {
                int row = wr * 64 + mf * 16 + (lane & 15);
                aF[mf] = *(const bf16x8*)(ldsA + row * 128 + (kb ^ ((row & 7) << 4)));
            }
            #pragma unroll
            for (int nf = 0; nf < 4; ++nf) {
                int row = wc * 64 + nf * 16 + (lane & 15);
                bF[nf] = *(const bf16x8*)(ldsB + row * 128 + (kb ^ ((row & 7) << 4)));
            }
            #pragma unroll
            for (int mf = 0; mf < 4; ++mf)
                #pragma unroll
                for (int nf = 0; nf < 4; ++nf)
                    acc[mf][nf] = __builtin_amdgcn_mfma_f32_16x16x32_bf16(
                        aF[mf], bF[nf], acc[mf][nf], 0, 0, 0);
        }
        __syncthreads();
    }

    #pragma unroll
    for (int mf = 0; mf < 4; ++mf) {
        #pragma unroll
        for (int nf = 0; nf < 4; ++nf) {
            int col   = n0 + wc * 64 + nf * 16 + (lane & 15);
            int rbase = m0 + wr * 64 + mf * 16 + (lane >> 4) * 4;
            float cb = (BIAS_MODE == 2) ? bias[col] : 0.f;
            #pragma unroll
            for (int e = 0; e < 4; ++e) {
                int row = rbase + e;
                float v = acc[mf][nf][e] * alpha;
                if (BIAS_MODE == 1) v += bias[row];
                if (BIAS_MODE == 2) v += cb;
                long off = (long)row * ldc + col;
                if (RESID) v += Rp[off];
                C[off] = (OutT)v;
            }
        }
    }
}

// ---------------- QK GEMM + fused exp + column partial sums (batched over z) ----------------
// P[z][j,i] = exp(0.0625 * sum_c kT[z][j,c] qT[z][i,c]); part[z][jblk][i] partial col sums
__launch_bounds__(256)
__global__ void gemm_qk_exp(const bf16* __restrict__ A, const bf16* __restrict__ B,
                            bf16* __restrict__ P, float* __restrict__ part) {
    __shared__ __align__(1024) char lds[34816];   // k-loop: 32KB; epi: bf16[128][132]=33792 + cs 1KB
    const long z = blockIdx.z;
    A += z * (4096L * 256); B += z * (4096L * 256);
    P += z * (4096L * 4096); part += z * (32L * 4096);

    const int m0 = blockIdx.y * 128;
    const int n0 = blockIdx.x * 128;
    const int lane = threadIdx.x & 63;
    const int wv = threadIdx.x >> 6;
    const int wr = wv >> 1, wc = wv & 1;

    f32x4 acc[4][4];
    #pragma unroll
    for (int i = 0; i < 4; ++i)
        #pragma unroll
        for (int j = 0; j < 4; ++j) acc[i][j] = f32x4{0.f, 0.f, 0.f, 0.f};

    char* ldsA = lds;
    char* ldsB = lds + 16384;

    for (int k0 = 0; k0 < 256; k0 += 64) {
        #pragma unroll
        for (int c = 0; c < 4; ++c) {
            int chunk  = wv * 4 + c;
            int ldsOff = chunk * 1024;
            int myOff  = ldsOff + lane * 16;
            int row    = myOff >> 7;
            int colB   = (myOff & 127) ^ ((row & 7) << 4);
            const char* srcA = (const char*)(A + (long)(m0 + row) * 256 + k0) + colB;
            __builtin_amdgcn_global_load_lds((const AS1 void*)srcA,
                                             (AS3 void*)(ldsA + ldsOff), 16, 0, 0);
            const char* srcB = (const char*)(B + (long)(n0 + row) * 256 + k0) + colB;
            __builtin_amdgcn_global_load_lds((const AS1 void*)srcB,
                                             (AS3 void*)(ldsB + ldsOff), 16, 0, 0);
        }
        __syncthreads();
        #pragma unroll
        for (int kk = 0; kk < 2; ++kk) {
            bf16x8 aF[4], bF[4];
            const int kb = kk * 64 + (lane >> 4) * 16;
            #pragma unroll
            for (int mf = 0; mf < 4; ++mf) {
                int row = wr * 64 + mf * 16 + (lane & 15);
                aF[mf] = *(const bf16x8*)(ldsA + row * 128 + (kb ^ ((row & 7) << 4)));
            }
            #pragma unroll
            for (int nf = 0; nf < 4; ++nf) {
                int row = wc * 64 + nf * 16 + (lane & 15);
                bF[nf] = *(const bf16x8*)(ldsB + row * 128 + (kb ^ ((row & 7) << 4)));
            }
            #pragma unroll
            for (int mf = 0; mf < 4; ++mf)
                #pragma unroll
                for (int nf = 0; nf < 4; ++nf)
                    acc[mf][nf] = __builtin_amdgcn_mfma_f32_16x16x32_bf16(
                        aF[mf], bF[nf], acc[mf][nf], 0, 0, 0);
        }
        __syncthreads();
    }

    // epilogue: exp, column sums, LDS-transposed coalesced bf16 write
    bf16*  pt = (bf16*)lds;                 // [128][132]
    float* cs = (float*)(lds + 33792);      // [2][128]
    float s[4] = {0.f, 0.f, 0.f, 0.f};
    #pragma unroll
    for (int mf = 0; mf < 4; ++mf) {
        #pragma unroll
        for (int nf = 0; nf < 4; ++nf) {
            int col = wc * 64 + nf * 16 + (lane & 15);
            int rb  = wr * 64 + mf * 16 + (lane >> 4) * 4;
            #pragma unroll
            for (int e = 0; e < 4; ++e) {
                float ev = __expf(acc[mf][nf][e] * 0.0625f);
                s[nf] += ev;
                pt[(rb + e) * 132 + col] = (bf16)ev;
            }
        }
    }
    #pragma unroll
    for (int nf = 0; nf < 4; ++nf) {
        s[nf] += __shfl_xor(s[nf], 16);
        s[nf] += __shfl_xor(s[nf], 32);
    }
    if (lane < 16) {
        #pragma unroll
        for (int nf = 0; nf < 4; ++nf)
            cs[wr * 128 + wc * 64 + nf * 16 + lane] = s[nf];
    }
    __syncthreads();
    if (threadIdx.x < 128)
        part[blockIdx.y * 4096 + n0 + threadIdx.x] = cs[threadIdx.x] + cs[128 + threadIdx.x];
    #pragma unroll
    for (int it = 0; it < 8; ++it) {
        int q   = it * 256 + threadIdx.x;
        int row = q >> 4;
        int c8  = (q & 15) << 3;
        bf16x8 v = *(const bf16x8*)(pt + row * 132 + c8);
        *(bf16x8*)(&P[(long)(m0 + row) * 4096 + n0 + c8]) = v;
    }
}

// ---------------- rl[z][i] = 1 / sum_{jblk} part[z][jblk][i] ----------------
__global__ void rl_calc(const float* __restrict__ part, float* __restrict__ rl) {
    const long z = blockIdx.y;
    int i = blockIdx.x * 256 + threadIdx.x;
    float s = 0.f;
    #pragma unroll
    for (int p = 0; p < 32; ++p) s += part[z * (32L * 4096) + p * 4096 + i];
    rl[z * 4096 + i] = 1.f / s;
}

// ---------------- vS[z][c,i] = v[z][c,i] * rl[z][i] ----------------
__global__ void v_scale(const bf16* __restrict__ v, const float* __restrict__ rl,
                        bf16* __restrict__ vS) {
    const long z = blockIdx.y;
    int idx = blockIdx.x * 256 + threadIdx.x;     // grid 512 -> 131072 bf16x8 chunks / batch
    int i0  = (idx * 8) & 4095;
    bf16x8 a = ((const bf16x8*)(v + z * (4096L * 256)))[idx];
    float4 r0 = *(const float4*)(rl + z * 4096 + i0);
    float4 r1 = *(const float4*)(rl + z * 4096 + i0 + 4);
    bf16x8 o;
    o[0] = (bf16)((float)a[0] * r0.x);
    o[1] = (bf16)((float)a[1] * r0.y);
    o[2] = (bf16)((float)a[2] * r0.z);
    o[3] = (bf16)((float)a[3] * r0.w);
    o[4] = (bf16)((float)a[4] * r1.x);
    o[5] = (bf16)((float)a[5] * r1.y);
    o[6] = (bf16)((float)a[6] * r1.z);
    o[7] = (bf16)((float)a[7] * r1.w);
    ((bf16x8*)(vS + z * (4096L * 256)))[idx] = o;
}

extern "C" void kernel_launch(void* const* d_in, const int* in_sizes, int n_in,
                              void* d_out, int out_size, void* d_ws, size_t ws_size,
                              hipStream_t stream) {
    const float* x   = (const float*)d_in[0];
    const float* gnw = (const float*)d_in[1];
    const float* gnb = (const float*)d_in[2];
    const float* wq  = (const float*)d_in[3];
    const float* bq  = (const float*)d_in[4];
    const float* wk  = (const float*)d_in[5];
    const float* bk  = (const float*)d_in[6];
    const float* wv  = (const float*)d_in[7];
    const float* bv  = (const float*)d_in[8];
    const float* wo  = (const float*)d_in[9];
    const float* bo  = (const float*)d_in[10];
    float* out = (float*)d_out;

    char* ws = (char*)d_ws;
    size_t off = 0;
    auto alloc = [&](size_t b) { char* p = ws + off; off += (b + 255) & ~(size_t)255; return p; };

    const long NC = 4096L * 256;          // per-batch [N,C] elems
    bf16* hT  = (bf16*)alloc(8 * NC * 2);
    bf16* qT  = (bf16*)alloc(8 * NC * 2);
    bf16* kT  = (bf16*)alloc(8 * NC * 2);
    bf16* vB  = (bf16*)alloc(8 * NC * 2);   // v[c,i]
    bf16* h2T = (bf16*)alloc(8 * NC * 2);
    bf16* wall = (bf16*)alloc(4 * 65536 * 2);       // wq|wk|wv|wo bf16, contiguous
    float* musd = (float*)alloc(256 * 2 * 4);
    bf16*  P    = (bf16*)alloc(4 * 4096L * 4096 * 2);   // exp(S), 4 batches (128MB)
    float* part = (float*)alloc(4 * 32L * 4096 * 4);
    float* rl   = (float*)alloc(4 * 4096 * 4);
    bf16*  vS   = (bf16*)alloc(4 * NC * 2);
    bf16* wqb = wall, *wkb = wall + 65536, *wvb = wall + 131072, *wob = wall + 196608;

    cvt_w4<<<256, 256, 0, stream>>>(wq, wk, wv, wo, wall);
    gn_stats<<<256, 256, 0, stream>>>(x, musd);
    gn_apply_t<<<512, 256, 0, stream>>>(x, musd, gnw, gnb, hT);

    // qT[i,c] = sum_k hT[i,k] wq[c,k] + bq[c]
    gemm_bt<2, false, bf16><<<dim3(2, 32, 8), 256, 0, stream>>>(
        hT, wqb, qT, bq, nullptr, 4096, 256, 256, 256, 256, 256, NC, 0, NC, 0, 1.f);
    gemm_bt<2, false, bf16><<<dim3(2, 32, 8), 256, 0, stream>>>(
        hT, wkb, kT, bk, nullptr, 4096, 256, 256, 256, 256, 256, NC, 0, NC, 0, 1.f);
    // v[c,i] = sum_k wv[c,k] hT[i,k] + bv[c]
    gemm_bt<1, false, bf16><<<dim3(32, 2, 8), 256, 0, stream>>>(
        wvb, hT, vB, bv, nullptr, 256, 4096, 256, 256, 256, 4096, 0, NC, NC, 0, 1.f);

    for (int g = 0; g < 2; ++g) {
        const long b0 = g * 4;
        // P[z][j,i] = exp(ST/16), part[z][jblk][i]
        gemm_qk_exp<<<dim3(32, 32, 4), 256, 0, stream>>>(
            kT + b0 * NC, qT + b0 * NC, P, part);
        rl_calc<<<dim3(16, 4), 256, 0, stream>>>(part, rl);
        v_scale<<<dim3(512, 4), 256, 0, stream>>>(vB + b0 * NC, rl, vS);
        // h2T[z][j,c] = sum_i P[z][j,i] vS[z][c,i]  -- full K, no split
        gemm_bt<0, false, bf16><<<dim3(2, 32, 4), 256, 0, stream>>>(
            P, vS, h2T + b0 * NC, nullptr, nullptr,
            4096, 256, 4096, 4096, 4096, 256, 4096L * 4096, NC, NC, 0, 1.f);
    }

    // out[o,j] = x[o,j] + bo[o] + sum_c wo[o,c] h2T[j,c]
    gemm_bt<1, true, float><<<dim3(32, 2, 8), 256, 0, stream>>>(
        wob, h2T, out, bo, x, 256, 4096, 256, 256, 256, 4096, 0, NC, NC, NC, 1.f);
}

// Round 4
// 372.111 us; speedup vs baseline: 2.0728x; 1.0261x over previous
//
#include <hip/hip_runtime.h>
#include <hip/hip_bf16.h>

typedef __bf16 bf16;
typedef __attribute__((ext_vector_type(8))) __bf16 bf16x8;
typedef __attribute__((ext_vector_type(4))) __bf16 bf16x4;
typedef __attribute__((ext_vector_type(4))) float f32x4;

#define AS1 __attribute__((address_space(1)))
#define AS3 __attribute__((address_space(3)))

// ---------------- all four weights fp32 -> bf16 (one launch) ----------------
__global__ void cvt_w4(const float* __restrict__ a0, const float* __restrict__ a1,
                       const float* __restrict__ a2, const float* __restrict__ a3,
                       bf16* __restrict__ o) {
    int idx = blockIdx.x * 256 + threadIdx.x;       // grid 256 -> 65536 float4s
    const float* srcs[4] = {a0, a1, a2, a3};
    float4 v = ((const float4*)srcs[idx >> 14])[idx & 16383];
    bf16x4 r; r[0] = (bf16)v.x; r[1] = (bf16)v.y; r[2] = (bf16)v.z; r[3] = (bf16)v.w;
    ((bf16x4*)o)[idx] = r;
}

// ---------------- concat q,k,v biases -> bqkv[768] ----------------
__global__ void cvt_b3(const float* __restrict__ bq, const float* __restrict__ bk,
                       const float* __restrict__ bv, float* __restrict__ o) {
    int t = threadIdx.x;
    o[t] = bq[t]; o[256 + t] = bk[t]; o[512 + t] = bv[t];
}

// ---------------- GroupNorm stats: one block per (b,g) ----------------
__global__ void gn_stats(const float* __restrict__ x, float* __restrict__ musd) {
    const int bg = blockIdx.x;
    const float4* p = (const float4*)(x + (long)bg * 32768);
    float s = 0.f, ss = 0.f;
    for (int i = threadIdx.x; i < 8192; i += 256) {
        float4 v = p[i];
        s  += v.x + v.y + v.z + v.w;
        ss += v.x*v.x + v.y*v.y + v.z*v.z + v.w*v.w;
    }
    for (int o = 32; o; o >>= 1) { s += __shfl_down(s, o); ss += __shfl_down(ss, o); }
    __shared__ float rs[4], rss[4];
    if ((threadIdx.x & 63) == 0) { rs[threadIdx.x >> 6] = s; rss[threadIdx.x >> 6] = ss; }
    __syncthreads();
    if (threadIdx.x == 0) {
        s  = rs[0] + rs[1] + rs[2] + rs[3];
        ss = rss[0] + rss[1] + rss[2] + rss[3];
        float mu  = s * (1.f / 32768.f);
        float var = ss * (1.f / 32768.f) - mu * mu;
        musd[bg * 2]     = mu;
        musd[bg * 2 + 1] = rsqrtf(var + 1e-5f);
    }
}

// ---------------- GroupNorm apply + transpose: x[b,c,i] -> hT[b,i,c] bf16 ----------------
__global__ void gn_apply_t(const float* __restrict__ x, const float* __restrict__ musd,
                           const float* __restrict__ gw, const float* __restrict__ gb,
                           bf16* __restrict__ hT) {
    const int b  = blockIdx.x >> 6;
    const int i0 = (blockIdx.x & 63) << 6;
    __shared__ bf16 tile[256][65];
    const int lane = threadIdx.x & 63, wv = threadIdx.x >> 6;
    const long xb = (long)b * (256L * 4096);
    for (int r = 0; r < 64; ++r) {
        int c = wv * 64 + r;
        int g = c >> 3;
        float mu   = musd[(b * 32 + g) * 2];
        float rstd = musd[(b * 32 + g) * 2 + 1];
        float v = x[xb + (long)c * 4096 + i0 + lane];
        tile[c][lane] = (bf16)((v - mu) * rstd * gw[c] + gb[c]);
    }
    __syncthreads();
    for (int it = 0; it < 8; ++it) {
        int q  = it * 256 + threadIdx.x;
        int il = q >> 5;
        int c8 = (q & 31) << 3;
        bf16x8 v;
        #pragma unroll
        for (int e = 0; e < 8; ++e) v[e] = tile[c8 + e][il];
        *(bf16x8*)(&hT[((long)b * 4096 + i0 + il) * 256 + c8]) = v;
    }
}

// ---------------- BT-GEMM: C[m,n] = alpha * sum_k A[m,k]*B[n,k] (+bias)(+resid) ----------------
// SPLITL2>0: blockIdx.z = zb*(1<<SPLITL2)+ks; A,B offset ks*K along k; C gets own z-slab.
template<int BIAS_MODE /*0 none,1 row,2 col*/, bool RESID, typename OutT, int SPLITL2 = 0>
__launch_bounds__(256)
__global__ void gemm_bt(const bf16* __restrict__ A, const bf16* __restrict__ B,
                        OutT* __restrict__ C,
                        const float* __restrict__ bias, const float* __restrict__ resid,
                        int M, int N, int K, int lda, int ldb, int ldc,
                        long sA, long sB, long sC, long sR, float alpha) {
    __shared__ __align__(1024) char lds[32768];
    const int zz = blockIdx.z;
    int zb, ks;
    if constexpr (SPLITL2 > 0) { zb = zz >> SPLITL2; ks = zz & ((1 << SPLITL2) - 1); }
    else { zb = zz; ks = 0; }
    A += (long)zb * sA + (long)ks * K;
    B += (long)zb * sB + (long)ks * K;
    if constexpr (SPLITL2 > 0) C += (long)zz * sC; else C += (long)zb * sC;
    const float* Rp = resid + (RESID ? (long)zb * sR : 0);

    const int m0 = blockIdx.y * 128;
    const int n0 = blockIdx.x * 128;
    const int lane = threadIdx.x & 63;
    const int wv = threadIdx.x >> 6;
    const int wr = wv >> 1, wc = wv & 1;

    f32x4 acc[4][4];
    #pragma unroll
    for (int i = 0; i < 4; ++i)
        #pragma unroll
        for (int j = 0; j < 4; ++j) acc[i][j] = f32x4{0.f, 0.f, 0.f, 0.f};

    char* ldsA = lds;
    char* ldsB = lds + 16384;

    for (int k0 = 0; k0 < K; k0 += 64) {
        #pragma unroll
        for (int c = 0; c < 4; ++c) {
            int chunk  = wv * 4 + c;
            int ldsOff = chunk * 1024;                  // wave-uniform dest
            int myOff  = ldsOff + lane * 16;
            int row    = myOff >> 7;
            int colB   = (myOff & 127) ^ ((row & 7) << 4);  // inverse-swizzled source
            const char* srcA = (const char*)(A + (long)(m0 + row) * lda + k0) + colB;
            __builtin_amdgcn_global_load_lds((const AS1 void*)srcA,
                                             (AS3 void*)(ldsA + ldsOff), 16, 0, 0);
            const char* srcB = (const char*)(B + (long)(n0 + row) * ldb + k0) + colB;
            __builtin_amdgcn_global_load_lds((const AS1 void*)srcB,
                                             (AS3 void*)(ldsB + ldsOff), 16, 0, 0);
        }
        __syncthreads();
        #pragma unroll
        for (int kk = 0; kk < 2; ++kk) {
            bf16x8 aF[4], bF[4];
            const int kb = kk * 64 + (lane >> 4) * 16;
            #pragma unroll
            for (int mf = 0; mf < 4; ++mf) {
                int row = wr * 64 + mf * 16 + (lane & 15);
                aF[mf] = *(const bf16x8*)(ldsA + row * 128 + (kb ^ ((row & 7) << 4)));
            }
            #pragma unroll
            for (int nf = 0; nf < 4; ++nf) {
                int row = wc * 64 + nf * 16 + (lane & 15);
                bF[nf] = *(const bf16x8*)(ldsB + row * 128 + (kb ^ ((row & 7) << 4)));
            }
            #pragma unroll
            for (int mf = 0; mf < 4; ++mf)
                #pragma unroll
                for (int nf = 0; nf < 4; ++nf)
                    acc[mf][nf] = __builtin_amdgcn_mfma_f32_16x16x32_bf16(
                        aF[mf], bF[nf], acc[mf][nf], 0, 0, 0);
        }
        __syncthreads();
    }

    #pragma unroll
    for (int mf = 0; mf < 4; ++mf) {
        #pragma unroll
        for (int nf = 0; nf < 4; ++nf) {
            int col   = n0 + wc * 64 + nf * 16 + (lane & 15);
            int rbase = m0 + wr * 64 + mf * 16 + (lane >> 4) * 4;
            float cb = (BIAS_MODE == 2) ? bias[col] : 0.f;
            #pragma unroll
            for (int e = 0; e < 4; ++e) {
                int row = rbase + e;
                float v = acc[mf][nf][e] * alpha;
                if (BIAS_MODE == 1) v += bias[row];
                if (BIAS_MODE == 2) v += cb;
                long off = (long)row * ldc + col;
                if (RESID) v += Rp[off];
                C[off] = (OutT)v;
            }
        }
    }
}

// ---------------- QK GEMM + fused exp + column partial sums (batched over z) ----------------
// A = kT slab (qkvT+256, lda 768), B = qT slab (qkvT, lda 768)
// P[z][j,i] = exp(0.0625 * sum_c k[j,c] q[i,c]); part[z][jblk][i] partial col sums
__launch_bounds__(256)
__global__ void gemm_qk_exp(const bf16* __restrict__ A, const bf16* __restrict__ B,
                            bf16* __restrict__ P, float* __restrict__ part) {
    __shared__ __align__(1024) char lds[34816];
    const long z = blockIdx.z;
    A += z * (4096L * 768); B += z * (4096L * 768);
    P += z * (4096L * 4096); part += z * (32L * 4096);

    const int m0 = blockIdx.y * 128;
    const int n0 = blockIdx.x * 128;
    const int lane = threadIdx.x & 63;
    const int wv = threadIdx.x >> 6;
    const int wr = wv >> 1, wc = wv & 1;

    f32x4 acc[4][4];
    #pragma unroll
    for (int i = 0; i < 4; ++i)
        #pragma unroll
        for (int j = 0; j < 4; ++j) acc[i][j] = f32x4{0.f, 0.f, 0.f, 0.f};

    char* ldsA = lds;
    char* ldsB = lds + 16384;

    for (int k0 = 0; k0 < 256; k0 += 64) {
        #pragma unroll
        for (int c = 0; c < 4; ++c) {
            int chunk  = wv * 4 + c;
            int ldsOff = chunk * 1024;
            int myOff  = ldsOff + lane * 16;
            int row    = myOff >> 7;
            int colB   = (myOff & 127) ^ ((row & 7) << 4);
            const char* srcA = (const char*)(A + (long)(m0 + row) * 768 + k0) + colB;
            __builtin_amdgcn_global_load_lds((const AS1 void*)srcA,
                                             (AS3 void*)(ldsA + ldsOff), 16, 0, 0);
            const char* srcB = (const char*)(B + (long)(n0 + row) * 768 + k0) + colB;
            __builtin_amdgcn_global_load_lds((const AS1 void*)srcB,
                                             (AS3 void*)(ldsB + ldsOff), 16, 0, 0);
        }
        __syncthreads();
        #pragma unroll
        for (int kk = 0; kk < 2; ++kk) {
            bf16x8 aF[4], bF[4];
            const int kb = kk * 64 + (lane >> 4) * 16;
            #pragma unroll
            for (int mf = 0; mf < 4; ++mf) {
                int row = wr * 64 + mf * 16 + (lane & 15);
                aF[mf] = *(const bf16x8*)(ldsA + row * 128 + (kb ^ ((row & 7) << 4)));
            }
            #pragma unroll
            for (int nf = 0; nf < 4; ++nf) {
                int row = wc * 64 + nf * 16 + (lane & 15);
                bF[nf] = *(const bf16x8*)(ldsB + row * 128 + (kb ^ ((row & 7) << 4)));
            }
            #pragma unroll
            for (int mf = 0; mf < 4; ++mf)
                #pragma unroll
                for (int nf = 0; nf < 4; ++nf)
                    acc[mf][nf] = __builtin_amdgcn_mfma_f32_16x16x32_bf16(
                        aF[mf], bF[nf], acc[mf][nf], 0, 0, 0);
        }
        __syncthreads();
    }

    // epilogue: exp, column sums, LDS-transposed coalesced bf16 write
    bf16*  pt = (bf16*)lds;                 // [128][132]
    float* cs = (float*)(lds + 33792);      // [2][128]
    float s[4] = {0.f, 0.f, 0.f, 0.f};
    #pragma unroll
    for (int mf = 0; mf < 4; ++mf) {
        #pragma unroll
        for (int nf = 0; nf < 4; ++nf) {
            int col = wc * 64 + nf * 16 + (lane & 15);
            int rb  = wr * 64 + mf * 16 + (lane >> 4) * 4;
            #pragma unroll
            for (int e = 0; e < 4; ++e) {
                float ev = __expf(acc[mf][nf][e] * 0.0625f);
                s[nf] += ev;
                pt[(rb + e) * 132 + col] = (bf16)ev;
            }
        }
    }
    #pragma unroll
    for (int nf = 0; nf < 4; ++nf) {
        s[nf] += __shfl_xor(s[nf], 16);
        s[nf] += __shfl_xor(s[nf], 32);
    }
    if (lane < 16) {
        #pragma unroll
        for (int nf = 0; nf < 4; ++nf)
            cs[wr * 128 + wc * 64 + nf * 16 + lane] = s[nf];
    }
    __syncthreads();
    if (threadIdx.x < 128)
        part[blockIdx.y * 4096 + n0 + threadIdx.x] = cs[threadIdx.x] + cs[128 + threadIdx.x];
    #pragma unroll
    for (int it = 0; it < 8; ++it) {
        int q   = it * 256 + threadIdx.x;
        int row = q >> 4;
        int c8  = (q & 15) << 3;
        bf16x8 v = *(const bf16x8*)(pt + row * 132 + c8);
        *(bf16x8*)(&P[(long)(m0 + row) * 4096 + n0 + c8]) = v;
    }
}

// ---------------- rl[z][i] = 1 / sum_{jblk} part[z][jblk][i] ----------------
__global__ void rl_calc(const float* __restrict__ part, float* __restrict__ rl) {
    const long z = blockIdx.y;
    int i = blockIdx.x * 256 + threadIdx.x;
    float s = 0.f;
    #pragma unroll
    for (int p = 0; p < 32; ++p) s += part[z * (32L * 4096) + p * 4096 + i];
    rl[z * 4096 + i] = 1.f / s;
}

// ---------------- vS[z][c,i] = qkvT[z][i, 512+c] * rl[z][i]  (transpose) ----------------
__global__ void v_scale_t(const bf16* __restrict__ qkvT, const float* __restrict__ rl,
                          bf16* __restrict__ vS) {
    const long z = blockIdx.y;
    const int i0 = blockIdx.x * 64;
    __shared__ bf16 t[256][72];          // [c][i]
    const int tid = threadIdx.x;
    #pragma unroll
    for (int it = 0; it < 8; ++it) {
        int q = it * 256 + tid;
        int r = q >> 5;                   // i within tile
        int c8 = (q & 31) << 3;
        bf16x8 v = *(const bf16x8*)(qkvT + (z * 4096 + i0 + r) * 768 + 512 + c8);
        float sc = rl[z * 4096 + i0 + r];
        #pragma unroll
        for (int e = 0; e < 8; ++e) t[c8 + e][r] = (bf16)((float)v[e] * sc);
    }
    __syncthreads();
    #pragma unroll
    for (int it = 0; it < 8; ++it) {
        int q = it * 256 + tid;
        int c = q >> 3;
        int i8 = (q & 7) << 3;
        bf16x8 o;
        #pragma unroll
        for (int e = 0; e < 8; ++e) o[e] = t[c][i8 + e];
        *(bf16x8*)(vS + z * (4096L * 256) + (long)c * 4096 + i0 + i8) = o;
    }
}

// ---------------- split-K reduce: 4 bf16 partial slabs -> bf16 (fp32 accumulate) ----------------
__global__ void reduce4(const bf16* __restrict__ p, bf16* __restrict__ out) {
    const long z = blockIdx.y;                    // batch within group
    int idx = blockIdx.x * 256 + threadIdx.x;     // 131072 bf16x8 chunks per batch
    const bf16x8* base = (const bf16x8*)p + z * 4 * 131072;
    bf16x8 a = base[idx], b = base[idx + 131072], c = base[idx + 262144], d = base[idx + 393216];
    bf16x8 o;
    #pragma unroll
    for (int e = 0; e < 8; ++e)
        o[e] = (bf16)((float)a[e] + (float)b[e] + (float)c[e] + (float)d[e]);
    ((bf16x8*)out)[z * 131072 + idx] = o;
}

extern "C" void kernel_launch(void* const* d_in, const int* in_sizes, int n_in,
                              void* d_out, int out_size, void* d_ws, size_t ws_size,
                              hipStream_t stream) {
    const float* x   = (const float*)d_in[0];
    const float* gnw = (const float*)d_in[1];
    const float* gnb = (const float*)d_in[2];
    const float* wq  = (const float*)d_in[3];
    const float* bq  = (const float*)d_in[4];
    const float* wk  = (const float*)d_in[5];
    const float* bk  = (const float*)d_in[6];
    const float* wv  = (const float*)d_in[7];
    const float* bv  = (const float*)d_in[8];
    const float* wo  = (const float*)d_in[9];
    const float* bo  = (const float*)d_in[10];
    float* out = (float*)d_out;

    char* ws = (char*)d_ws;
    size_t off = 0;
    auto alloc = [&](size_t b) { char* p = ws + off; off += (b + 255) & ~(size_t)255; return p; };

    const long NC = 4096L * 256;          // per-batch [N,C] elems
    const long ST = 4096L * 768;          // per-batch qkvT stride
    bf16* hT   = (bf16*)alloc(8 * NC * 2);
    bf16* qkvT = (bf16*)alloc(8 * ST * 2);          // [b][i][q|k|v channels]
    bf16* h2T  = (bf16*)alloc(8 * NC * 2);
    bf16* wall = (bf16*)alloc(4 * 65536 * 2);       // wq|wk|wv|wo bf16, contiguous
    float* bqkv = (float*)alloc(768 * 4);
    float* musd = (float*)alloc(256 * 2 * 4);
    bf16*  P    = (bf16*)alloc(4 * 4096L * 4096 * 2);   // exp(S), 4 batches (128MB)
    float* part = (float*)alloc(4 * 32L * 4096 * 4);
    float* rl   = (float*)alloc(4 * 4096 * 4);
    bf16*  vS   = (bf16*)alloc(4 * NC * 2);
    bf16*  pvp  = (bf16*)alloc(16 * NC * 2);            // 4 batches x 4 K-splits
    bf16* wob = wall + 196608;

    cvt_w4<<<256, 256, 0, stream>>>(wq, wk, wv, wo, wall);
    cvt_b3<<<1, 256, 0, stream>>>(bq, bk, bv, bqkv);
    gn_stats<<<256, 256, 0, stream>>>(x, musd);
    gn_apply_t<<<512, 256, 0, stream>>>(x, musd, gnw, gnb, hT);

    // qkvT[i, 0:768] = sum_k hT[i,k] * wqkv[o,k] + bqkv[o]
    gemm_bt<2, false, bf16><<<dim3(6, 32, 8), 256, 0, stream>>>(
        hT, wall, qkvT, bqkv, nullptr, 4096, 768, 256, 256, 256, 768, NC, 0, ST, 0, 1.f);

    for (int g = 0; g < 2; ++g) {
        const long b0 = g * 4;
        // P[z][j,i] = exp(ST/16), part[z][jblk][i]
        gemm_qk_exp<<<dim3(32, 32, 4), 256, 0, stream>>>(
            qkvT + b0 * ST + 256, qkvT + b0 * ST, P, part);
        rl_calc<<<dim3(16, 4), 256, 0, stream>>>(part, rl);
        v_scale_t<<<dim3(64, 4), 256, 0, stream>>>(qkvT + b0 * ST, rl, vS);
        // pvp[z*4+ks][j,c] = sum_{i in split ks} P[z][j,i] vS[z][c,i]
        gemm_bt<0, false, bf16, 2><<<dim3(2, 32, 16), 256, 0, stream>>>(
            P, vS, pvp, nullptr, nullptr,
            4096, 256, 1024, 4096, 4096, 256, 4096L * 4096, NC, NC, 0, 1.f);
        reduce4<<<dim3(512, 4), 256, 0, stream>>>(pvp, h2T + b0 * NC);
    }

    // out[o,j] = x[o,j] + bo[o] + sum_c wo[o,c] h2T[j,c]
    gemm_bt<1, true, float><<<dim3(32, 2, 8), 256, 0, stream>>>(
        wob, h2T, out, bo, x, 256, 4096, 256, 256, 256, 4096, 0, NC, NC, NC, 1.f);
}